// Round 1
// baseline (148.506 us; speedup 1.0000x reference)
//
#include <hip/hip_runtime.h>

// Chamfer distance: B=4, N=M=8192, D=3, fp32 inputs, scalar fp32 output.
// Compute-bound on the fp32 vector ALU (no fp32 MFMA on CDNA4).

#define QT 256      // queries per block = threads per block
#define TT 1024     // target points staged per block
#define B_ 4
#define N_ 8192
#define SPLIT (N_ / TT)   // 8-way split of target dim for occupancy

__global__ __launch_bounds__(QT) void chamfer_min_kernel(
    const float* __restrict__ q, const float* __restrict__ t,
    unsigned int* __restrict__ minbuf, int Nq, int Nt) {
  __shared__ float sx[TT], sy[TT], sz[TT];

  const int b = blockIdx.z;
  const int qi = blockIdx.x * QT + threadIdx.x;
  const int tstart = blockIdx.y * TT;

  // Cooperative coalesced stage of 1024 target points (12 KB) into SoA LDS.
  const float* tb = t + ((size_t)b * Nt + tstart) * 3;
  for (int idx = threadIdx.x; idx < TT * 3; idx += QT) {
    float v = tb[idx];
    int p = idx / 3;
    int c = idx - p * 3;
    if (c == 0) sx[p] = v;
    else if (c == 1) sy[p] = v;
    else sz[p] = v;
  }
  __syncthreads();

  // Query point in registers.
  const float* qp = q + ((size_t)b * Nq + qi) * 3;
  const float qx = qp[0], qy = qp[1], qz = qp[2];

  // 8 independent min accumulators -> ILP against FMA/min dep chains.
  float best[8];
#pragma unroll
  for (int k = 0; k < 8; ++k) best[k] = 3.4e38f;

  for (int j = 0; j < TT; j += 8) {
#pragma unroll
    for (int k = 0; k < 8; ++k) {
      // Broadcast LDS reads (uniform address across wave: conflict-free).
      float dx = sx[j + k] - qx;
      float dy = sy[j + k] - qy;
      float dz = sz[j + k] - qz;
      float d2 = fmaf(dx, dx, fmaf(dy, dy, dz * dz));
      best[k] = fminf(best[k], d2);
    }
  }

  float m0 = fminf(fminf(best[0], best[1]), fminf(best[2], best[3]));
  float m1 = fminf(fminf(best[4], best[5]), fminf(best[6], best[7]));
  float bmin = fminf(m0, m1);

  // Non-negative floats: uint bit-pattern comparison == float comparison.
  atomicMin(&minbuf[(size_t)b * Nq + qi], __float_as_uint(bmin));
}

__global__ __launch_bounds__(256) void chamfer_finalize(
    const unsigned int* __restrict__ minbuf, float* __restrict__ out,
    int total, float scale) {
  int i = blockIdx.x * 256 + threadIdx.x;
  float v = (i < total) ? sqrtf(__uint_as_float(minbuf[i])) : 0.0f;

  // Wave64 reduce.
#pragma unroll
  for (int off = 32; off > 0; off >>= 1) v += __shfl_down(v, off, 64);

  __shared__ float ws[4];
  int lane = threadIdx.x & 63;
  int wid = threadIdx.x >> 6;
  if (lane == 0) ws[wid] = v;
  __syncthreads();
  if (threadIdx.x == 0) {
    float s = (ws[0] + ws[1]) + (ws[2] + ws[3]);
    atomicAdd(out, s * scale);
  }
}

extern "C" void kernel_launch(void* const* d_in, const int* in_sizes, int n_in,
                              void* d_out, int out_size, void* d_ws, size_t ws_size,
                              hipStream_t stream) {
  const float* pred = (const float*)d_in[0];  // [B, N, 3]
  const float* gt   = (const float*)d_in[1];  // [B, M, 3]
  float* out = (float*)d_out;                 // scalar
  unsigned int* minbuf = (unsigned int*)d_ws; // 2 * B * N uints

  const size_t min_elems = (size_t)2 * B_ * N_;
  hipMemsetAsync(minbuf, 0xFF, min_elems * sizeof(unsigned int), stream); // +inf-ish
  hipMemsetAsync(out, 0, sizeof(float), stream);

  dim3 grid(N_ / QT, SPLIT, B_);
  // pred -> gt mins
  chamfer_min_kernel<<<grid, QT, 0, stream>>>(pred, gt, minbuf, N_, N_);
  // gt -> pred mins
  chamfer_min_kernel<<<grid, QT, 0, stream>>>(gt, pred, minbuf + (size_t)B_ * N_, N_, N_);

  const int total = 2 * B_ * N_;
  // mean over B*N each direction; both counts equal -> single scale.
  chamfer_finalize<<<(total + 255) / 256, 256, 0, stream>>>(
      minbuf, out, total, 1.0f / (float)(B_ * N_));
}

// Round 2
// 143.068 us; speedup vs baseline: 1.0380x; 1.0380x over previous
//
#include <hip/hip_runtime.h>

// Chamfer distance: B=4, N=M=8192, D=3, fp32. VALU compute-bound.
// Strategy: pack (x,y,z,|p|^2) float4; score = |t|^2 - 2 q.t via 3 FMA/pair,
// targets are wave-uniform -> scalar loads; add |q|^2 once at the end.

#define QT 256      // queries per block = threads per block
#define TT 1024     // target points per block (split dimension)
#define B_ 4
#define N_ 8192
#define SPLIT (N_ / TT)

// pts4: [2][B][N] float4 (x,y,z,|p|^2). minbuf: [2][B][N] uint (init FLT_MAX).
__global__ __launch_bounds__(256) void chamfer_pack(
    const float* __restrict__ pred, const float* __restrict__ gt,
    float4* __restrict__ pts4, unsigned int* __restrict__ minbuf) {
  const int i = blockIdx.x * 256 + threadIdx.x;   // 0 .. 2*B*N-1
  const int half = B_ * N_;
  const float* src = (i < half) ? pred : gt;
  const int k = (i < half) ? i : i - half;
  const float x = src[3 * k], y = src[3 * k + 1], z = src[3 * k + 2];
  pts4[i] = make_float4(x, y, z, fmaf(x, x, fmaf(y, y, z * z)));
  minbuf[i] = 0x7F7FFFFFu;  // FLT_MAX bits
}

// One launch covers both directions: blockIdx.z in [0, 2*B).
__global__ __launch_bounds__(QT) void chamfer_min2(
    const float4* __restrict__ pts4, unsigned int* __restrict__ minbuf) {
  const int dir = blockIdx.z / B_;          // 0: pred->gt, 1: gt->pred
  const int b   = blockIdx.z % B_;
  const int qi  = blockIdx.x * QT + threadIdx.x;
  const int tstart = blockIdx.y * TT;

  // Query point (divergent, coalesced float4 load).
  const float4 qv = pts4[((size_t)dir * B_ + b) * N_ + qi];
  const float nqx = -2.0f * qv.x, nqy = -2.0f * qv.y, nqz = -2.0f * qv.z;
  const float q2 = qv.w;

  // Targets: wave-uniform addresses -> scalar loads, L2-resident.
  const float4* __restrict__ tgt =
      pts4 + ((size_t)(1 - dir) * B_ + b) * N_ + tstart;

  float best0 = 3.4e38f, best1 = 3.4e38f, best2 = 3.4e38f, best3 = 3.4e38f;
  for (int j = 0; j < TT; j += 8) {
    float s[8];
#pragma unroll
    for (int k = 0; k < 8; ++k) {
      const float4 t = tgt[j + k];
      s[k] = fmaf(nqx, t.x, fmaf(nqy, t.y, fmaf(nqz, t.z, t.w)));
    }
    // fminf chains -> v_min3_f32 fusion; 4 independent accumulators for ILP.
    best0 = fminf(fminf(best0, s[0]), s[1]);
    best1 = fminf(fminf(best1, s[2]), s[3]);
    best2 = fminf(fminf(best2, s[4]), s[5]);
    best3 = fminf(fminf(best3, s[6]), s[7]);
  }
  const float best = fminf(fminf(best0, best1), fminf(best2, best3));
  const float d2 = fmaxf(q2 + best, 0.0f);   // clamp: rounding can go slightly <0
  atomicMin(&minbuf[((size_t)dir * B_ + b) * N_ + qi], __float_as_uint(d2));
}

__global__ __launch_bounds__(256) void chamfer_finalize(
    const unsigned int* __restrict__ minbuf, float* __restrict__ out,
    int total, float scale) {
  const int i = blockIdx.x * 256 + threadIdx.x;
  float v = (i < total) ? sqrtf(__uint_as_float(minbuf[i])) : 0.0f;
#pragma unroll
  for (int off = 32; off > 0; off >>= 1) v += __shfl_down(v, off, 64);
  __shared__ float ws[4];
  const int lane = threadIdx.x & 63;
  const int wid = threadIdx.x >> 6;
  if (lane == 0) ws[wid] = v;
  __syncthreads();
  if (threadIdx.x == 0) {
    atomicAdd(out, ((ws[0] + ws[1]) + (ws[2] + ws[3])) * scale);
  }
}

extern "C" void kernel_launch(void* const* d_in, const int* in_sizes, int n_in,
                              void* d_out, int out_size, void* d_ws, size_t ws_size,
                              hipStream_t stream) {
  const float* pred = (const float*)d_in[0];  // [B, N, 3]
  const float* gt   = (const float*)d_in[1];  // [B, M, 3]
  float* out = (float*)d_out;

  const size_t npts = (size_t)2 * B_ * N_;    // 65536
  float4* pts4 = (float4*)d_ws;                         // 1 MiB
  unsigned int* minbuf = (unsigned int*)((char*)d_ws + npts * sizeof(float4)); // 256 KiB

  hipMemsetAsync(out, 0, sizeof(float), stream);

  chamfer_pack<<<(int)(npts / 256), 256, 0, stream>>>(pred, gt, pts4, minbuf);

  dim3 grid(N_ / QT, SPLIT, 2 * B_);
  chamfer_min2<<<grid, QT, 0, stream>>>(pts4, minbuf);

  const int total = (int)npts;
  chamfer_finalize<<<(total + 255) / 256, 256, 0, stream>>>(
      minbuf, out, total, 1.0f / (float)(B_ * N_));
}